// Round 2
// baseline (306.030 us; speedup 1.0000x reference)
//
#include <hip/hip_runtime.h>
#include <hip/hip_bf16.h>
#include <stdint.h>

// ---------------------------------------------------------------------------
// SparseLinear: y[B,N] = x[B,M] @ W^T + bias, W given as CSR.
// R6: fix R5's counted-vmcnt schedule.
//   R5 post-mortem: per-phase vmcnt(4) gave every stage only a 2-phase
//   latency budget (stage S first-read at phase S+3 START, guarantee at
//   S+2's wait) -> loop paced at ~latency/2 per phase; plus all sync was
//   inline asm, which the waitcnt-insertion pass treats conservatively
//   (can insert vmcnt(0) before asm while LDS-DMA pending). Result: 36%
//   MfmaUtil, identical to the 1-phase structure (m218's "8ph-drain0").
//   Fixes:
//   - Front-loaded stage schedule per 4-phase group: ph1 stages A0'+B0'
//     (4 loads), ph2 stages A1' (2), ph3 stages B1' (2), ph4 none.
//     Every half now has a stage->first-read gap of 4 phases.
//   - In-order vmcnt ledger (per-wave outstanding = 8 at each wait):
//     ph1 vmcnt(6) retires prev-group A1'' (read next phase),
//     ph2 vmcnt(6) retires prev-group B1'' (read next phase),
//     ph3 NO WAIT, ph4 vmcnt(4) retires this group's A0'+B0' (read next
//     phase). 3-phase budget for every stage; one wait-free phase/group.
//   - WAR: each half's old data is last ds_read >= 1 full barrier before
//     the overwriting stage is issued (issue order is program order).
//   - All sync via builtins (s_waitcnt imm / s_barrier / setprio /
//     sched_barrier(0) once per phase) -- no inline asm in the hot loop.
// ---------------------------------------------------------------------------

#define B_DIM 4096
#define M_DIM 4096
#define N_DIM 4096
#define NNZ_ROW 819

typedef __attribute__((ext_vector_type(8))) __bf16 bf16x8;
typedef __attribute__((ext_vector_type(4))) float f32x4;

__device__ __forceinline__ unsigned short f32_to_bf16(float f) {
    union { float f; unsigned int u; } v;
    v.f = f;
    unsigned int r = v.u + 0x7FFFu + ((v.u >> 16) & 1u);  // RNE
    return (unsigned short)(r >> 16);
}

__device__ __forceinline__ void load_lds16(const void* g, void* l) {
    __builtin_amdgcn_global_load_lds(
        (const __attribute__((address_space(1))) void*)g,
        (__attribute__((address_space(3))) void*)l,
        16, 0, 0);
}

// ---- prologue 1: densify one W row per block (verified R2) ----------------
__global__ __launch_bounds__(256) void densify_w(
    const float* __restrict__ wval,
    const int* __restrict__ cols,
    unsigned short* __restrict__ wb) {
    __shared__ __attribute__((aligned(16))) unsigned short row_s[M_DIM];  // 8 KB
    const int row = blockIdx.x;
    const int tid = threadIdx.x;
    uint4* rs4 = (uint4*)row_s;
    rs4[tid]       = make_uint4(0u, 0u, 0u, 0u);
    rs4[tid + 256] = make_uint4(0u, 0u, 0u, 0u);
    __syncthreads();
    const size_t base = (size_t)row * NNZ_ROW;
    for (int j = tid; j < NNZ_ROW; j += 256) {
        const int c = cols[base + j];
        row_s[c] = f32_to_bf16(wval[base + j]);
    }
    __syncthreads();
    uint4* dst = (uint4*)(wb + (size_t)row * M_DIM);
    dst[tid]       = rs4[tid];
    dst[tid + 256] = rs4[tid + 256];
}

// ---- prologue 2: X fp32 -> bf16 -------------------------------------------
__global__ __launch_bounds__(256) void cvt_x_bf16(
    const float4* __restrict__ x, uint4* __restrict__ y, int n8) {
    int i = blockIdx.x * 256 + threadIdx.x;
    if (i >= n8) return;
    const float4 a = x[2 * i];
    const float4 b = x[2 * i + 1];
    union { ushort ush[8]; uint4 u4; } o;
    o.ush[0] = f32_to_bf16(a.x); o.ush[1] = f32_to_bf16(a.y);
    o.ush[2] = f32_to_bf16(a.z); o.ush[3] = f32_to_bf16(a.w);
    o.ush[4] = f32_to_bf16(b.x); o.ush[5] = f32_to_bf16(b.y);
    o.ush[6] = f32_to_bf16(b.z); o.ush[7] = f32_to_bf16(b.w);
    y[i] = o.u4;
}

// ---------------------------------------------------------------------------
// Stage one 128-row half-tile (128 rows x 64 k, bf16) for K-offset kt.
// LDS dest is LINEAR: wave w covers segments {2w, 2w+1}; each instruction
// writes 1024B = 8 rows at (uniform base + lane*16). The lane's 16B slot is
// (row r = seg*8 + (l>>3), chunk' = l&7); LDS(r, c') holds global chunk
// c' ^ (r&7), and (r&7)==(l>>3), so src chunk = (l&7) ^ (l>>3).
// ---------------------------------------------------------------------------
__device__ __forceinline__ void stage_half(
    const unsigned short* __restrict__ src,  // global [4096][4096] bf16 bits
    int grow0,                               // global row of half's row 0
    int kt,                                  // k element offset of this K-tile
    unsigned short* dst,                     // LDS half base (ushort*)
    int w, int l) {
#pragma unroll
    for (int j = 0; j < 2; ++j) {
        const int seg = w * 2 + j;                // 0..15
        const int r   = seg * 8 + (l >> 3);       // local row 0..127
        const int cg  = (l >> 3) ^ (l & 7);       // inverse-swizzled src chunk
        load_lds16(src + (size_t)(grow0 + r) * M_DIM + kt + cg * 8,
                   dst + seg * 512);              // 512 ush = 1024 B
    }
}

// ---------------------------------------------------------------------------
// One phase: compute block-level C-quadrant (MA,NB) of the current K-tile
// (waves tile the 128x128 quadrant as 2x4 of 64x32), stage part of the NEXT
// K-tile per SK: 0 = {A0',B0'} (4 loads), 1 = {A1'}, 2 = {B1'}, 3 = none.
// WAITN: vmcnt target after the stage issue (-1 = no wait).
// Fragment read: row ra = quad + l15 (+16*mf), chunk c = ks*4 + (l>>4),
// stored at chunk' = c ^ (ra&7) = c ^ (l&7). 2-way bank access (free).
// ---------------------------------------------------------------------------
template <int MA, int NB, int SK, int WAITN>
__device__ __forceinline__ void phase_op(
    const unsigned short* As_c, const unsigned short* Bs_c,
    unsigned short* As_n, unsigned short* Bs_n,
    const unsigned short* __restrict__ Xb, const unsigned short* __restrict__ Wb,
    int bm0, int bn0, int kn, bool do_stage,
    int wr, int wc, int w, int l, f32x4 (&acc)[2][4][2][2]) {
    const int l15 = l & 15;
    const int lg  = l >> 4;
    const int lx  = l & 7;
    const int ck0 = (lg ^ lx) << 3;          // ushort offset, k-chunk ks=0
    const int ck1 = ((4 + lg) ^ lx) << 3;    // k-chunk ks=1

    const unsigned short* Ab = As_c + (MA * 128 + wr * 64 + l15) * 64;
    const unsigned short* Bb = Bs_c + (NB * 128 + wc * 32 + l15) * 64;

    bf16x8 af[4][2], bfr[2][2];
#pragma unroll
    for (int mf = 0; mf < 4; ++mf) {
        af[mf][0] = *(const bf16x8*)(Ab + mf * 1024 + ck0);
        af[mf][1] = *(const bf16x8*)(Ab + mf * 1024 + ck1);
    }
#pragma unroll
    for (int nf = 0; nf < 2; ++nf) {
        bfr[nf][0] = *(const bf16x8*)(Bb + nf * 1024 + ck0);
        bfr[nf][1] = *(const bf16x8*)(Bb + nf * 1024 + ck1);
    }

    if (do_stage) {
        if constexpr (SK == 0) {
            stage_half(Xb, bm0,       kn, As_n,        w, l);
            stage_half(Wb, bn0,       kn, Bs_n,        w, l);
        }
        if constexpr (SK == 1) stage_half(Xb, bm0 + 128, kn, As_n + 8192, w, l);
        if constexpr (SK == 2) stage_half(Wb, bn0 + 128, kn, Bs_n + 8192, w, l);
    }

    // Counted wait (builtin, gfx9 encoding: vmcnt[3:0], expcnt[6:4]=7,
    // lgkmcnt[11:8]=0xF -> lgkm/exp fields are no-ops). Never 0 in the loop.
    if constexpr (WAITN >= 0) __builtin_amdgcn_s_waitcnt(0x0F70 | WAITN);
    __builtin_amdgcn_s_barrier();   // publish retired stages to all waves

    __builtin_amdgcn_s_setprio(1);
#pragma unroll
    for (int mf = 0; mf < 4; ++mf)
#pragma unroll
        for (int nf = 0; nf < 2; ++nf) {
            acc[MA][mf][NB][nf] = __builtin_amdgcn_mfma_f32_16x16x32_bf16(
                af[mf][0], bfr[nf][0], acc[MA][mf][NB][nf], 0, 0, 0);
            acc[MA][mf][NB][nf] = __builtin_amdgcn_mfma_f32_16x16x32_bf16(
                af[mf][1], bfr[nf][1], acc[MA][mf][NB][nf], 0, 0, 0);
        }
    __builtin_amdgcn_s_setprio(0);
    __builtin_amdgcn_s_barrier();   // end of phase: readers done, WAR-safe
    __builtin_amdgcn_sched_barrier(0);  // pin next phase's ds_reads behind
}

// ---- main GEMM: C[b,n] = sum_k Xb[b,k]*Wb[n,k] + bias[n] -------------------
__global__ __launch_bounds__(512, 2) void gemm_bt_bias(
    const unsigned short* __restrict__ Xb,   // [B][M] bf16 bits
    const unsigned short* __restrict__ Wb,   // [N][M] bf16 bits
    const float* __restrict__ bias,          // [N]
    float* __restrict__ out)                 // [B][N]
{
    // 4 fixed buffers: A/B x double-buffer. 4 x 32 KB = 128 KB LDS.
    __shared__ __attribute__((aligned(16))) unsigned short As0[16384];
    __shared__ __attribute__((aligned(16))) unsigned short Bs0[16384];
    __shared__ __attribute__((aligned(16))) unsigned short As1[16384];
    __shared__ __attribute__((aligned(16))) unsigned short Bs1[16384];

    const int tid = threadIdx.x;
    const int w   = tid >> 6;     // wave 0..7
    const int l   = tid & 63;
    const int wr  = w >> 2;       // 0..1  (64-row slice within quadrant)
    const int wc  = w & 3;        // 0..3  (32-col slice within quadrant)

    // bijective XCD swizzle (256 blocks, 8 XCDs, 32 contiguous per XCD)
    const int wg  = blockIdx.y * 16 + blockIdx.x;
    const int idx = ((wg & 7) << 5) | (wg >> 3);
    const int bm0 = (idx >> 4) * 256;   // batch rows
    const int bn0 = (idx & 15) * 256;   // N cols

    f32x4 acc[2][4][2][2];
#pragma unroll
    for (int a = 0; a < 2; ++a)
#pragma unroll
        for (int b = 0; b < 4; ++b)
#pragma unroll
            for (int c = 0; c < 2; ++c)
#pragma unroll
                for (int d = 0; d < 2; ++d) acc[a][b][c][d] = (f32x4)0.0f;

    // ---- prologue: stage K-tile 0 fully into buf0, drain, barrier ----
    stage_half(Xb, bm0,       0, As0,        w, l);
    stage_half(Wb, bn0,       0, Bs0,        w, l);
    stage_half(Xb, bm0 + 128, 0, As0 + 8192, w, l);
    stage_half(Wb, bn0 + 128, 0, Bs0 + 8192, w, l);
    __builtin_amdgcn_s_waitcnt(0x0F70);   // vmcnt(0), cold start only
    __builtin_amdgcn_s_barrier();

    // ---- main loop: 2 K-tiles (8 phases) per iteration ----
    // Ledger (per-wave, in-order vmcnt; steady-state outstanding = 8 at
    // each wait): ph1 vmcnt(6) retires prev A1'' (first read ph2);
    // ph2 vmcnt(6) retires prev B1'' (first read ph3); ph3 no wait;
    // ph4 vmcnt(4) retires this group's A0'+B0' (first read next ph1).
    // Every stage: issued 3 phases before its retiring wait, which is one
    // phase (wait + barrier) before its first ds_read. Tail: fewer
    // outstanding -> waits are no-ops.
#pragma unroll 1
    for (int kt = 0; kt < M_DIM; kt += 128) {
        const int k1 = kt + 64;    // staged during phases 1-3 (always valid)
        const int k2 = kt + 128;   // staged during phases 5-7
        const bool s2 = (k2 < M_DIM);
        phase_op<0,0,0, 6>(As0,Bs0, As1,Bs1, Xb,Wb, bm0,bn0, k1, true, wr,wc,w,l, acc);
        phase_op<1,0,1, 6>(As0,Bs0, As1,Bs1, Xb,Wb, bm0,bn0, k1, true, wr,wc,w,l, acc);
        phase_op<1,1,2,-1>(As0,Bs0, As1,Bs1, Xb,Wb, bm0,bn0, k1, true, wr,wc,w,l, acc);
        phase_op<0,1,3, 4>(As0,Bs0, As1,Bs1, Xb,Wb, bm0,bn0, k1, true, wr,wc,w,l, acc);
        phase_op<0,0,0, 6>(As1,Bs1, As0,Bs0, Xb,Wb, bm0,bn0, k2, s2,   wr,wc,w,l, acc);
        phase_op<1,0,1, 6>(As1,Bs1, As0,Bs0, Xb,Wb, bm0,bn0, k2, s2,   wr,wc,w,l, acc);
        phase_op<1,1,2,-1>(As1,Bs1, As0,Bs0, Xb,Wb, bm0,bn0, k2, s2,   wr,wc,w,l, acc);
        phase_op<0,1,3, 4>(As1,Bs1, As0,Bs0, Xb,Wb, bm0,bn0, k2, s2,   wr,wc,w,l, acc);
    }

    // ---- epilogue: D elem r of acc -> row = (l>>4)*4+r, col = l&15 ----
    const int l15 = l & 15;
    const int lg  = l >> 4;
#pragma unroll
    for (int nb = 0; nb < 2; ++nb)
#pragma unroll
        for (int nf = 0; nf < 2; ++nf) {
            const int col = bn0 + nb * 128 + wc * 32 + nf * 16 + l15;
            const float bv = bias[col];
#pragma unroll
            for (int ma = 0; ma < 2; ++ma)
#pragma unroll
                for (int mf = 0; mf < 4; ++mf) {
                    const int row0 = bm0 + ma * 128 + wr * 64 + mf * 16 + lg * 4;
#pragma unroll
                    for (int r = 0; r < 4; ++r)
                        out[(size_t)(row0 + r) * N_DIM + col] =
                            acc[ma][mf][nb][nf][r] + bv;
                }
        }
}

// ---------------------------------------------------------------------------

extern "C" void kernel_launch(void* const* d_in, const int* in_sizes, int n_in,
                              void* d_out, int out_size, void* d_ws, size_t ws_size,
                              hipStream_t stream) {
    const float* x       = (const float*)d_in[0];
    const float* wval    = (const float*)d_in[1];
    const float* bias    = (const float*)d_in[2];
    const int*   cols    = (const int*)d_in[4];
    float* out = (float*)d_out;

    // workspace: Wb [N*M bf16] (32 MiB) | Xb [B*M bf16] (32 MiB)
    unsigned short* Wb = (unsigned short*)d_ws;
    unsigned short* Xb = Wb + (size_t)N_DIM * M_DIM;

    densify_w<<<dim3(N_DIM), dim3(256), 0, stream>>>(wval, cols, Wb);
    {
        int n8 = (B_DIM * M_DIM) / 8;
        cvt_x_bf16<<<dim3(n8 / 256), dim3(256), 0, stream>>>(
            (const float4*)x, (uint4*)Xb, n8);
    }
    gemm_bt_bias<<<dim3(N_DIM / 256, B_DIM / 256), dim3(512), 0, stream>>>(
        Xb, Wb, bias, out);
}

// Round 3
// 280.122 us; speedup vs baseline: 1.0925x; 1.0925x over previous
//
#include <hip/hip_runtime.h>
#include <hip/hip_bf16.h>
#include <stdint.h>

// ---------------------------------------------------------------------------
// SparseLinear: y[B,N] = x[B,M] @ W^T + bias, W given as CSR.
// R7: fix the REAL bottleneck -- LDS read volume (fragment re-reads).
//   R5/R6 post-mortem: phase time 1481 cyc vs ~155 cyc MFMA; per phase each
//   of 8 waves read 12 KB from LDS (96 KB/CU-phase) ~= the whole phase at
//   LDS BW. Quadrant-per-phase re-read A frags per NB and B frags per MA:
//   48 KB/wave/K-tile where dedup needs 24 KB. vmcnt schedule was never the
//   pacer (L2-resident panels, 3-phase budget >> latency; two schedules
//   measured identical).
//   Fix: phases = (MA, KS) pairs. ph1: read af(0,k0) + B(k0) [8 reads],
//   MFMA MA=0/k0 x both NB; ph2: read af(1,k0) [4], reuse B regs; ph3:
//   af(0,k1)+B(k1) [8]; ph4: af(1,k1) [4]. 24 reads/wave/K-tile (was 48).
//   Per-accumulator order still k0-then-k1 -> bit-identical results.
//   Stage schedule: ph1 A0'+B0' (4 loads), ph2 B1' (2), ph3 A1' (2), ph4 -.
//   Ledger (in-order vmcnt, per-wave): t-1 ph4 vmcnt(2) publishes A0,B0,B1(t)
//   (read from t ph1); t ph1 vmcnt(4) publishes A1(t) (read from t ph2);
//   ph2/ph3 no wait. Tail peeled: last tile ph1 waits vmcnt(0) (fixes a
//   latent R6 tail race on A1 of the final tile).
//   Also: densify_w + cvt_x merged into one prologue launch.
// ---------------------------------------------------------------------------

#define B_DIM 4096
#define M_DIM 4096
#define N_DIM 4096
#define NNZ_ROW 819

typedef __attribute__((ext_vector_type(8))) __bf16 bf16x8;
typedef __attribute__((ext_vector_type(4))) float f32x4;

__device__ __forceinline__ unsigned short f32_to_bf16(float f) {
    union { float f; unsigned int u; } v;
    v.f = f;
    unsigned int r = v.u + 0x7FFFu + ((v.u >> 16) & 1u);  // RNE
    return (unsigned short)(r >> 16);
}

__device__ __forceinline__ void load_lds16(const void* g, void* l) {
    __builtin_amdgcn_global_load_lds(
        (const __attribute__((address_space(1))) void*)g,
        (__attribute__((address_space(3))) void*)l,
        16, 0, 0);
}

// ---- merged prologue: densify W rows (blocks 0..4095) + X fp32->bf16
//      (blocks 4096..12287, 8 floats/thread, exact grid) --------------------
__global__ __launch_bounds__(256) void prep(
    const float* __restrict__ wval,
    const int* __restrict__ cols,
    unsigned short* __restrict__ wb,
    const float4* __restrict__ x,
    uint4* __restrict__ xb) {
    const int tid = threadIdx.x;
    if (blockIdx.x >= N_DIM) {
        const int i = (blockIdx.x - N_DIM) * 256 + tid;   // 0 .. 2M-1, exact
        const float4 a = x[2 * i];
        const float4 b = x[2 * i + 1];
        union { ushort ush[8]; uint4 u4; } o;
        o.ush[0] = f32_to_bf16(a.x); o.ush[1] = f32_to_bf16(a.y);
        o.ush[2] = f32_to_bf16(a.z); o.ush[3] = f32_to_bf16(a.w);
        o.ush[4] = f32_to_bf16(b.x); o.ush[5] = f32_to_bf16(b.y);
        o.ush[6] = f32_to_bf16(b.z); o.ush[7] = f32_to_bf16(b.w);
        xb[i] = o.u4;
        return;
    }
    __shared__ __attribute__((aligned(16))) unsigned short row_s[M_DIM];  // 8 KB
    const int row = blockIdx.x;
    uint4* rs4 = (uint4*)row_s;
    rs4[tid]       = make_uint4(0u, 0u, 0u, 0u);
    rs4[tid + 256] = make_uint4(0u, 0u, 0u, 0u);
    __syncthreads();
    const size_t base = (size_t)row * NNZ_ROW;
    for (int j = tid; j < NNZ_ROW; j += 256) {
        const int c = cols[base + j];
        row_s[c] = f32_to_bf16(wval[base + j]);
    }
    __syncthreads();
    uint4* dst = (uint4*)(wb + (size_t)row * M_DIM);
    dst[tid]       = rs4[tid];
    dst[tid + 256] = rs4[tid + 256];
}

// ---------------------------------------------------------------------------
// Stage one 128-row half-tile (128 rows x 64 k, bf16) for K-offset kt.
// LDS dest LINEAR: wave w covers segments {2w,2w+1}; lane's 16B slot is
// (row r = seg*8 + (l>>3), chunk' = l&7); LDS(r,c') holds global chunk
// c' ^ (r&7) = (l&7) ^ (l>>3).
// ---------------------------------------------------------------------------
__device__ __forceinline__ void stage_half(
    const unsigned short* __restrict__ src,
    int grow0, int kt, unsigned short* dst, int w, int l) {
#pragma unroll
    for (int j = 0; j < 2; ++j) {
        const int seg = w * 2 + j;
        const int r   = seg * 8 + (l >> 3);
        const int cg  = (l >> 3) ^ (l & 7);
        load_lds16(src + (size_t)(grow0 + r) * M_DIM + kt + cg * 8,
                   dst + seg * 512);
    }
}

// ---------------------------------------------------------------------------
// One phase = (MA, KS): MFMA the MA-quadrant-row for k-chunk KS over both NB.
// Reads: af(MA,KS) always (4x ds_read_b128); B(KS) for both NB iff RDB
// (4x; persists in bfr across the following phase). Stage per SK:
// 0 = A0'+B0' (4 loads), 1 = B1' (2), 2 = A1' (2), 3 = none.
// Fragment addressing: row = base + l15, chunk c = KS*4 + (l>>4), stored at
// chunk' = c ^ (row&7) = c ^ (l&7)  (2-way bank access, free).
// ---------------------------------------------------------------------------
template <int MA, int KS, bool RDB, int SK, int WAITN>
__device__ __forceinline__ void phase_op(
    const unsigned short* As_c, const unsigned short* Bs_c,
    unsigned short* As_n, unsigned short* Bs_n,
    const unsigned short* __restrict__ Xb, const unsigned short* __restrict__ Wb,
    int bm0, int bn0, int kn, bool do_stage,
    int wr, int wc, int w, int l,
    bf16x8 (&bfr)[2][2], f32x4 (&acc)[2][4][2][2]) {
    const int l15 = l & 15;
    const int lg  = l >> 4;
    const int lx  = l & 7;
    const int ck  = ((KS * 4 + lg) ^ lx) << 3;   // ushort offset within row

    const unsigned short* Ab = As_c + (MA * 128 + wr * 64 + l15) * 64;
    bf16x8 af[4];
#pragma unroll
    for (int mf = 0; mf < 4; ++mf)
        af[mf] = *(const bf16x8*)(Ab + mf * 1024 + ck);

    if constexpr (RDB) {
#pragma unroll
        for (int nb = 0; nb < 2; ++nb) {
            const unsigned short* Bb = Bs_c + (nb * 128 + wc * 32 + l15) * 64;
#pragma unroll
            for (int nf = 0; nf < 2; ++nf)
                bfr[nb][nf] = *(const bf16x8*)(Bb + nf * 1024 + ck);
        }
    }

    if (do_stage) {
        if constexpr (SK == 0) {
            stage_half(Xb, bm0,       kn, As_n,        w, l);
            stage_half(Wb, bn0,       kn, Bs_n,        w, l);
        }
        if constexpr (SK == 1) stage_half(Wb, bn0 + 128, kn, Bs_n + 8192, w, l);
        if constexpr (SK == 2) stage_half(Xb, bm0 + 128, kn, As_n + 8192, w, l);
    }

    // Counted wait (gfx9 enc: vmcnt[3:0]; expcnt=7/lgkmcnt=0xF are no-ops).
    if constexpr (WAITN >= 0) __builtin_amdgcn_s_waitcnt(0x0F70 | WAITN);
    __builtin_amdgcn_s_barrier();

    __builtin_amdgcn_s_setprio(1);
#pragma unroll
    for (int mf = 0; mf < 4; ++mf)
#pragma unroll
        for (int nb = 0; nb < 2; ++nb)
#pragma unroll
            for (int nf = 0; nf < 2; ++nf)
                acc[MA][mf][nb][nf] = __builtin_amdgcn_mfma_f32_16x16x32_bf16(
                    af[mf], bfr[nb][nf], acc[MA][mf][nb][nf], 0, 0, 0);
    __builtin_amdgcn_s_setprio(0);
    __builtin_amdgcn_s_barrier();
    __builtin_amdgcn_sched_barrier(0);
}

// ---- main GEMM: C[b,n] = sum_k Xb[b,k]*Wb[n,k] + bias[n] -------------------
__global__ __launch_bounds__(512, 2) void gemm_bt_bias(
    const unsigned short* __restrict__ Xb,   // [B][M] bf16 bits
    const unsigned short* __restrict__ Wb,   // [N][M] bf16 bits
    const float* __restrict__ bias,          // [N]
    float* __restrict__ out)                 // [B][N]
{
    __shared__ __attribute__((aligned(16))) unsigned short As0[16384];
    __shared__ __attribute__((aligned(16))) unsigned short Bs0[16384];
    __shared__ __attribute__((aligned(16))) unsigned short As1[16384];
    __shared__ __attribute__((aligned(16))) unsigned short Bs1[16384];

    const int tid = threadIdx.x;
    const int w   = tid >> 6;     // wave 0..7
    const int l   = tid & 63;
    const int wr  = w >> 2;       // 0..1  (64-row slice within quadrant)
    const int wc  = w & 3;        // 0..3  (32-col slice within quadrant)

    // bijective XCD swizzle (256 blocks, 8 XCDs, 32 contiguous per XCD)
    const int wg  = blockIdx.y * 16 + blockIdx.x;
    const int idx = ((wg & 7) << 5) | (wg >> 3);
    const int bm0 = (idx >> 4) * 256;   // batch rows
    const int bn0 = (idx & 15) * 256;   // N cols

    f32x4 acc[2][4][2][2];
#pragma unroll
    for (int a = 0; a < 2; ++a)
#pragma unroll
        for (int b = 0; b < 4; ++b)
#pragma unroll
            for (int c = 0; c < 2; ++c)
#pragma unroll
                for (int d = 0; d < 2; ++d) acc[a][b][c][d] = (f32x4)0.0f;

    bf16x8 bfr[2][2];

    // ---- prologue: stage K-tile 0 fully into buf0, drain, barrier ----
    stage_half(Xb, bm0,       0, As0,        w, l);
    stage_half(Wb, bn0,       0, Bs0,        w, l);
    stage_half(Xb, bm0 + 128, 0, As0 + 8192, w, l);
    stage_half(Wb, bn0 + 128, 0, Bs0 + 8192, w, l);
    __builtin_amdgcn_s_waitcnt(0x0F70);   // vmcnt(0), cold start only
    __builtin_amdgcn_s_barrier();

#define TILE4(AC, BC, AN, BN, KN, DS)                                          \
    phase_op<0, 0, true , 0,  4>(AC, BC, AN, BN, Xb, Wb, bm0, bn0, KN, DS,     \
                                 wr, wc, w, l, bfr, acc);                      \
    phase_op<1, 0, false, 1, -1>(AC, BC, AN, BN, Xb, Wb, bm0, bn0, KN, DS,     \
                                 wr, wc, w, l, bfr, acc);                      \
    phase_op<0, 1, true , 2, -1>(AC, BC, AN, BN, Xb, Wb, bm0, bn0, KN, DS,     \
                                 wr, wc, w, l, bfr, acc);                      \
    phase_op<1, 1, false, 3,  2>(AC, BC, AN, BN, Xb, Wb, bm0, bn0, KN, DS,     \
                                 wr, wc, w, l, bfr, acc);

    // ---- main loop: 2 K-tiles per iter; 31 full iters + peeled tail ----
#pragma unroll 1
    for (int kt = 0; kt < M_DIM - 128; kt += 128) {
        const int k1 = kt + 64;
        const int k2 = kt + 128;
        TILE4(As0, Bs0, As1, Bs1, k1, true)
        TILE4(As1, Bs1, As0, Bs0, k2, true)
    }
    // tile 62 (buf0): stages tile 63 into buf1 (k = 4032)
    TILE4(As0, Bs0, As1, Bs1, M_DIM - 64, true)
    // tile 63 (buf1): no staging; ph1 drains the in-flight A1(63) (vmcnt 0,
    // tail-only) -- fixes the latent R6 tail race.
    phase_op<0, 0, true , 3,  0>(As1, Bs1, As0, Bs0, Xb, Wb, bm0, bn0, 0, false,
                                 wr, wc, w, l, bfr, acc);
    phase_op<1, 0, false, 3, -1>(As1, Bs1, As0, Bs0, Xb, Wb, bm0, bn0, 0, false,
                                 wr, wc, w, l, bfr, acc);
    phase_op<0, 1, true , 3, -1>(As1, Bs1, As0, Bs0, Xb, Wb, bm0, bn0, 0, false,
                                 wr, wc, w, l, bfr, acc);
    phase_op<1, 1, false, 3, -1>(As1, Bs1, As0, Bs0, Xb, Wb, bm0, bn0, 0, false,
                                 wr, wc, w, l, bfr, acc);
#undef TILE4

    // ---- epilogue: D elem r of acc -> row = (l>>4)*4+r, col = l&15 ----
    const int l15 = l & 15;
    const int lg  = l >> 4;
#pragma unroll
    for (int nb = 0; nb < 2; ++nb)
#pragma unroll
        for (int nf = 0; nf < 2; ++nf) {
            const int col = bn0 + nb * 128 + wc * 32 + nf * 16 + l15;
            const float bv = bias[col];
#pragma unroll
            for (int ma = 0; ma < 2; ++ma)
#pragma unroll
                for (int mf = 0; mf < 4; ++mf) {
                    const int row0 = bm0 + ma * 128 + wr * 64 + mf * 16 + lg * 4;
#pragma unroll
                    for (int r = 0; r < 4; ++r)
                        out[(size_t)(row0 + r) * N_DIM + col] =
                            acc[ma][mf][nb][nf][r] + bv;
                }
        }
}

// ---------------------------------------------------------------------------

extern "C" void kernel_launch(void* const* d_in, const int* in_sizes, int n_in,
                              void* d_out, int out_size, void* d_ws, size_t ws_size,
                              hipStream_t stream) {
    const float* x       = (const float*)d_in[0];
    const float* wval    = (const float*)d_in[1];
    const float* bias    = (const float*)d_in[2];
    const int*   cols    = (const int*)d_in[4];
    float* out = (float*)d_out;

    // workspace: Wb [N*M bf16] (32 MiB) | Xb [B*M bf16] (32 MiB)
    unsigned short* Wb = (unsigned short*)d_ws;
    unsigned short* Xb = Wb + (size_t)N_DIM * M_DIM;

    // merged prologue: 4096 densify blocks + 8192 cvt blocks
    prep<<<dim3(N_DIM + (B_DIM * M_DIM) / 8 / 256), dim3(256), 0, stream>>>(
        wval, cols, Wb, (const float4*)x, (uint4*)Xb);
    gemm_bt_bias<<<dim3(N_DIM / 256, B_DIM / 256), dim3(512), 0, stream>>>(
        Xb, Wb, bias, out);
}